// Round 15
// baseline (66.486 us; speedup 1.0000x reference)
//
#include <hip/hip_runtime.h>
#include <math.h>

#define SIZE 512
#define NPTS 128

typedef float v2f __attribute__((ext_vector_type(2)));

// exact tanh/clip correction for one banded segment (rare path)
__device__ __forceinline__ float seg_corr(float ax, float ay,
                                          float bx, float by, float cr)
{
    const float K    = 100000.0f;
    const float PI_F = 3.14159265358979f;
    const float HPI  = 1.57079632679490f;
    const float ANG_LO = 4.4721397e-3f;   // acos(1-1e-5)
    const float ANG_HI = 3.1371205f;      // acos(-1+1e-5)

    const float dt  = fmaf(ax, bx, ay * by);
    const float acr = fabsf(cr), adt = fabsf(dt);
    const float mn  = fminf(acr, adt);
    const float mxv = fmaxf(acr, adt);
    const float t   = mn * __builtin_amdgcn_rcpf(mxv);
    const float s2  = t * t;
    float q = fmaf(-0.01172120f, s2, 0.05265332f);
    q = fmaf(q, s2, -0.11643287f);
    q = fmaf(q, s2,  0.19354346f);
    q = fmaf(q, s2, -0.33262347f);
    q = fmaf(q, s2,  0.99997726f);
    float an = t * q;
    an = (acr > adt) ? (HPI  - an) : an;
    an = (dt < 0.0f) ? (PI_F - an) : an;
    const float anc = __builtin_amdgcn_fmed3f(an, ANG_LO, ANG_HI);

    const float e  = __expf(2.0f * K * cr);
    const float th = fmaf(-2.0f, __builtin_amdgcn_rcpf(e + 1.0f), 1.0f);

    // tanh*clip(ang) - sign(cr)*ang
    return fmaf(th, anc, -__builtin_copysignf(an, cr));
}

__global__ __launch_bounds__(256) void contour_mask_kernel(
    const float* __restrict__ contour, float* __restrict__ out)
{
    __shared__ float2 c[NPTS + 1];   // sentinel c[128] = c[0]

    const int tid = threadIdx.x;
    if (tid < NPTS)  c[tid]  = ((const float2*)contour)[tid];
    if (tid == NPTS) c[NPTS] = ((const float2*)contour)[0];
    __syncthreads();

    const int p = blockIdx.x * 256 + tid;
    const int i = p >> 9;         // row  (first meshgrid coord)
    const int j = p & (SIZE - 1); // col  (second meshgrid coord)

    const float mx = (float)i * (1.0f / SIZE);
    const float my = (float)j * (1.0f / SIZE);

    const float INV2PI = 0.15915494309190f;
    const float CTHR   = 6e-5f;   // tanh band halfwidth (cr units)

    float ax = c[0].x - mx;
    float ay = c[0].y - my;
    float uy = (ay > 0.0f) ? 1.0f : 0.0f;   // carried [ay>0]

    v2f   W    = {0.0f, 0.0f};   // packed signed crossing count
    float corr = 0.0f;           // exact correction (banded segments only)

    #pragma unroll 1
    for (int g = 0; g < NPTS / 8; ++g) {
        const int base = g * 8;

        #pragma unroll
        for (int t = 0; t < 4; ++t) {
            const float2 cn0 = c[base + 2 * t + 1];
            const float2 cn1 = c[base + 2 * t + 2];

            // packed diffs / cross for segments (2t, 2t+1)
            const v2f CX = {cn0.x, cn1.x};
            const v2f CY = {cn0.y, cn1.y};
            const v2f BX = CX - mx;                  // v_pk_add
            const v2f BY = CY - my;
            const v2f AX = {ax, BX.x};               // carried-diff chain
            const v2f AY = {ay, BY.x};
            const v2f CR = AY * BX - AX * BY;        // pk_mul + pk_fma

            // crossing count: d = [ay>0]-[by>0]; count d iff d*cr > 0
            const float vy0 = (BY.x > 0.0f) ? 1.0f : 0.0f;
            const float vy1 = (BY.y > 0.0f) ? 1.0f : 0.0f;
            const v2f D = v2f{uy, vy0} - v2f{vy0, vy1};   // pk_add
            const v2f M = D * CR;                         // pk_mul
            const v2f T = {(M.x > 0.0f) ? D.x : 0.0f,
                           (M.y > 0.0f) ? D.y : 0.0f};
            W += T;                                       // pk_add

            // per-segment band trigger, values already live (R14 lesson:
            // group-granularity triggers 8x too often; keep per-seg)
            if (__any(fabsf(CR.x) < CTHR))
                corr += seg_corr(AX.x, AY.x, BX.x, BY.x, CR.x);
            if (__any(fabsf(CR.y) < CTHR))
                corr += seg_corr(AX.y, AY.y, BX.y, BY.y, CR.y);

            ax = BX.y; ay = BY.y; uy = vy1;
        }
    }

    const float r = fmaf(corr, INV2PI, W.x + W.y);
    out[p] = __builtin_amdgcn_fmed3f(r, 0.0f, 1.0f);
}

extern "C" void kernel_launch(void* const* d_in, const int* in_sizes, int n_in,
                              void* d_out, int out_size, void* d_ws, size_t ws_size,
                              hipStream_t stream) {
    const float* contour = (const float*)d_in[0];
    float* out = (float*)d_out;

    const int total = SIZE * SIZE;   // 262144
    const int block = 256;
    const int grid  = total / block; // 1024 blocks -> 4096 waves, 4/SIMD

    contour_mask_kernel<<<grid, block, 0, stream>>>(contour, out);
}

// Round 16
// 64.521 us; speedup vs baseline: 1.0305x; 1.0305x over previous
//
#include <hip/hip_runtime.h>
#include <math.h>

#define SIZE 512
#define NPTS 128

__global__ __launch_bounds__(256) void contour_mask_kernel(
    const float* __restrict__ contour, float* __restrict__ out)
{
    __shared__ float2 c[NPTS + 1];   // sentinel c[128] = c[0]

    const int tid = threadIdx.x;
    if (tid < NPTS)  c[tid]  = ((const float2*)contour)[tid];
    if (tid == NPTS) c[NPTS] = ((const float2*)contour)[0];
    __syncthreads();

    const int p = blockIdx.x * 256 + tid;
    const int i = p >> 9;         // row  (first meshgrid coord)
    const int j = p & (SIZE - 1); // col  (second meshgrid coord)

    const float mx = (float)i * (1.0f / SIZE);
    const float my = (float)j * (1.0f / SIZE);

    const float K    = 100000.0f;
    const float PI_F = 3.14159265358979f;
    const float HPI  = 1.57079632679490f;
    const float INV2PI = 0.15915494309190f;
    const float ANG_LO = 4.4721397e-3f;   // acos(1-1e-5)
    const float ANG_HI = 3.1371205f;      // acos(-1+1e-5)
    const float CTHR = 6e-5f;             // tanh band

    float ax = c[0].x - mx;
    float ay = c[0].y - my;
    float uy = (ay > 0.0f) ? 1.0f : 0.0f;   // carried sign flag [ay>0]

    float w    = 0.0f;   // signed crossing count
    float corr = 0.0f;   // exact tanh/clip correction (banded segments only)

    #pragma unroll 8
    for (int n = 0; n < NPTS; ++n) {
        const float2 cn = c[n + 1];          // imm-offset ds_read_b64
        const float bx = cn.x - mx;
        const float by = cn.y - my;
        const float cr = fmaf(ay, bx, -ax * by);  // diff.y*roll.x - diff.x*roll.y

        // crossing count: d = [ay>0]-[by>0]; count d iff d*cr > 0
        const float vy = (by > 0.0f) ? 1.0f : 0.0f;
        const float d  = uy - vy;
        const float m  = d * cr;
        w += (m > 0.0f) ? d : 0.0f;

        // rare path: lane in tanh band -> exact correction for THIS segment,
        // using the already-live ax/ay/bx/by/cr (no recompute, no group).
        if (__any(fabsf(cr) < CTHR)) {
            const float dt  = fmaf(ax, bx, ay * by);
            const float acr = fabsf(cr), adt = fabsf(dt);
            const float mn  = fminf(acr, adt);
            const float mxv = fmaxf(acr, adt);
            const float t   = mn * __builtin_amdgcn_rcpf(mxv);
            const float s2  = t * t;
            float q = fmaf(-0.01172120f, s2, 0.05265332f);
            q = fmaf(q, s2, -0.11643287f);
            q = fmaf(q, s2,  0.19354346f);
            q = fmaf(q, s2, -0.33262347f);
            q = fmaf(q, s2,  0.99997726f);
            float an = t * q;
            an = (acr > adt) ? (HPI  - an) : an;
            an = (dt < 0.0f) ? (PI_F - an) : an;
            const float anc = __builtin_amdgcn_fmed3f(an, ANG_LO, ANG_HI);

            const float e  = __expf(2.0f * K * cr);
            const float th = fmaf(-2.0f, __builtin_amdgcn_rcpf(e + 1.0f), 1.0f);

            // corr += tanh*clip(ang) - sign(cr)*ang
            corr += fmaf(th, anc, -__builtin_copysignf(an, cr));
        }

        ax = bx; ay = by; uy = vy;
    }

    const float r = fmaf(corr, INV2PI, w);
    out[p] = __builtin_amdgcn_fmed3f(r, 0.0f, 1.0f);
}

extern "C" void kernel_launch(void* const* d_in, const int* in_sizes, int n_in,
                              void* d_out, int out_size, void* d_ws, size_t ws_size,
                              hipStream_t stream) {
    const float* contour = (const float*)d_in[0];
    float* out = (float*)d_out;

    const int total = SIZE * SIZE;   // 262144
    const int block = 256;
    const int grid  = total / block; // 1024 blocks -> 4096 waves, 4/SIMD

    contour_mask_kernel<<<grid, block, 0, stream>>>(contour, out);
}